// Round 6
// baseline (673.426 us; speedup 1.0000x reference)
//
#include <hip/hip_runtime.h>
#include <math.h>

#define BATCH 2
#define SEQ 2048
#define DMODEL 2048
#define NH 16
#define HD 128

typedef __bf16 bf16x8 __attribute__((ext_vector_type(8)));
typedef __bf16 bf16x4 __attribute__((ext_vector_type(4)));
typedef float f32x4 __attribute__((ext_vector_type(4)));
typedef float f32x16 __attribute__((ext_vector_type(16)));

// async global->LDS, 16B per lane; dst must be wave-uniform, HW adds lane*16
#define GLL16(dst, src)                                                          \
  __builtin_amdgcn_global_load_lds(                                              \
      (const __attribute__((address_space(1))) void*)(src),                      \
      (__attribute__((address_space(3))) void*)(dst), 16, 0, 0)

// =====================================================================
// split fp32 -> bf16 hi + bf16 lo  (hi = rne(v), lo = rne(v - hi))
// =====================================================================
__global__ __launch_bounds__(256) void split_fp32(const float* __restrict__ src,
                                                  __bf16* __restrict__ hi,
                                                  __bf16* __restrict__ lo) {
  const size_t i = (size_t)blockIdx.x * 256 + threadIdx.x;
  const float4 v = ((const float4*)src)[i];
  bf16x4 h, L;
  h[0] = (__bf16)v.x; h[1] = (__bf16)v.y; h[2] = (__bf16)v.z; h[3] = (__bf16)v.w;
  L[0] = (__bf16)(v.x - (float)h[0]);
  L[1] = (__bf16)(v.y - (float)h[1]);
  L[2] = (__bf16)(v.z - (float)h[2]);
  L[3] = (__bf16)(v.w - (float)h[3]);
  ((bf16x4*)hi)[i] = h;
  ((bf16x4*)lo)[i] = L;
}

// =====================================================================
// Deep-pipelined split GEMM (NT): C[4096,2048] = (Ah+Al).((Bh+Bl))^T
// via K'=3K: segments (Ah,Bh),(Al,Bh),(Ah,Bl) over K'=6144.
// BM=256 BN=128 BK=64, 8 waves (4Mx2N), per-wave 64x64.
// LDS 128 KiB: A triple-buffered (3x32K), B double-buffered (2x16K).
// Stage order per tile t: B(t+1), A0(t+2), A1(t+2) -> vmcnt(4) at tile top
// (counted, never 0 until the last tile). 4 phases/tile, bare s_barrier,
// setprio around MFMA. XOR chunk-swizzle (l&7)^(l>>3) applied on the
// global source (gload_lds dest stays linear) and on fragment reads.
// =====================================================================
template <int EMIT>
__global__ __launch_bounds__(512, 2) void gemm8(const __bf16* __restrict__ Ah,
                                                const __bf16* __restrict__ Al,
                                                const __bf16* __restrict__ Bh,
                                                const __bf16* __restrict__ Bl,
                                                void* __restrict__ Cout) {
  extern __shared__ char sm[];          // 128 KiB dynamic
  constexpr int NT = 96;                // 6144 / 64
  const int tid = threadIdx.x;
  const int l = tid & 63, w = tid >> 6;
  const int lg = l >> 4, lm = l & 15;
  const int wr = w >> 1, wc = w & 1;    // wave grid 4M x 2N

  // XCD-aware 2D block decode: XCD X gets a 4mb x 8nb rectangle
  const int bid = (int)blockIdx.x;
  const int X = bid & 7, sub = bid >> 3;
  const int mb = (X & 3) * 4 + (sub >> 3);
  const int nb = (X >> 2) * 8 + (sub & 7);
  const int m0 = mb * 256, n0 = nb * 128;

  const __bf16* segA[3] = {Ah, Al, Ah};
  const __bf16* segB[3] = {Bh, Bh, Bl};

  // staging lane constants: 8-row groups, swizzled 16B chunk
  const int srow = l >> 3;                   // 0..7
  const int co = ((l & 7) ^ srow) * 8;       // element offset of 16B chunk

  // LDS map: A slots at 0/32K/64K (each 256 rows x 128B); B at 96K/112K
  char* const Abuf = sm;
  char* const Bbuf = sm + 98304;

  // ---- staging helpers (issue order inside matters for vmcnt counting) ----
  auto stageB = [&](int tb) {                // 2 gll per thread
    char* bd = Bbuf + (tb & 1) * 16384;
    const __bf16* sb = segB[tb >> 5];
    const int kw = (tb & 31) * 64;
#pragma unroll
    for (int j = 0; j < 2; ++j)
      GLL16(bd + (w * 2 + j) * 1024,
            sb + (size_t)(n0 + (w * 2 + j) * 8 + srow) * 2048 + kw + co);
  };
  auto stageAu = [&](int ta, int slot, int u) {   // 2 gll per thread
    char* ad = Abuf + slot * 32768 + u * 16384;
    const __bf16* sa = segA[ta >> 5];
    const int kw = (ta & 31) * 64;
#pragma unroll
    for (int j = 0; j < 2; ++j)
      GLL16(ad + (w * 2 + j) * 1024,
            sa + (size_t)(m0 + u * 128 + (w * 2 + j) * 8 + srow) * 2048 + kw + co);
  };

  // ---- prologue: A(0)->slot0; B(0); A(1)->slot1 ----
  stageAu(0, 0, 0); stageAu(0, 0, 1);
  stageB(0);
  stageAu(1, 1, 0); stageAu(1, 1, 1);

  f32x4 acc[4][4];
#pragma unroll
  for (int i = 0; i < 4; ++i)
#pragma unroll
    for (int j = 0; j < 4; ++j) { f32x4 z = {0.f, 0.f, 0.f, 0.f}; acc[i][j] = z; }

  int sA = 0, sA2 = 2;   // A read slot (t%3), A stage slot ((t+2)%3)
  const int swz = lm & 7;

  for (int t = 0; t < NT; ++t) {
    // ---- tile top: counted wait + barrier (all waves' tile-t data visible)
    if (t + 1 < NT) { asm volatile("s_waitcnt vmcnt(4)" ::: "memory"); }
    else            { asm volatile("s_waitcnt vmcnt(0)" ::: "memory"); }
    __builtin_amdgcn_sched_barrier(0);
    __builtin_amdgcn_s_barrier();

    const char* Ab = Abuf + sA * 32768;
    const char* Bb = Bbuf + (t & 1) * 16384;

    bf16x8 b0[4], b1[4], a[2];

    // ---- phase 0: stage B(t+1); read B(k0) + A(i0,i1;k0); 8 MFMA ----
    if (t + 1 < NT) stageB(t + 1);
#pragma unroll
    for (int j = 0; j < 4; ++j)
      b0[j] = *(const bf16x8*)(Bb + (wc * 64 + j * 16 + lm) * 128 + ((lg ^ swz) << 4));
#pragma unroll
    for (int i = 0; i < 2; ++i)
      a[i] = *(const bf16x8*)(Ab + (wr * 64 + i * 16 + lm) * 128 + ((lg ^ swz) << 4));
    __builtin_amdgcn_s_barrier();
    __builtin_amdgcn_s_setprio(1);
#pragma unroll
    for (int i = 0; i < 2; ++i)
#pragma unroll
      for (int j = 0; j < 4; ++j)
        acc[i][j] = __builtin_amdgcn_mfma_f32_16x16x32_bf16(a[i], b0[j], acc[i][j], 0, 0, 0);
    __builtin_amdgcn_s_setprio(0);

    // ---- phase 1: stage A0(t+2); read B(k1) + A(i0,i1;k1); 8 MFMA ----
    if (t + 2 < NT) stageAu(t + 2, sA2, 0);
#pragma unroll
    for (int j = 0; j < 4; ++j)
      b1[j] = *(const bf16x8*)(Bb + (wc * 64 + j * 16 + lm) * 128 + (((4 + lg) ^ swz) << 4));
#pragma unroll
    for (int i = 0; i < 2; ++i)
      a[i] = *(const bf16x8*)(Ab + (wr * 64 + i * 16 + lm) * 128 + (((4 + lg) ^ swz) << 4));
    __builtin_amdgcn_s_barrier();
    __builtin_amdgcn_s_setprio(1);
#pragma unroll
    for (int i = 0; i < 2; ++i)
#pragma unroll
      for (int j = 0; j < 4; ++j)
        acc[i][j] = __builtin_amdgcn_mfma_f32_16x16x32_bf16(a[i], b1[j], acc[i][j], 0, 0, 0);
    __builtin_amdgcn_s_setprio(0);

    // ---- phase 2: stage A1(t+2); read A(i2,i3;k0); reuse B(k0); 8 MFMA ----
    if (t + 2 < NT) stageAu(t + 2, sA2, 1);
#pragma unroll
    for (int i = 0; i < 2; ++i)
      a[i] = *(const bf16x8*)(Ab + (wr * 64 + (2 + i) * 16 + lm) * 128 + ((lg ^ swz) << 4));
    __builtin_amdgcn_s_barrier();
    __builtin_amdgcn_s_setprio(1);
#pragma unroll
    for (int i = 0; i < 2; ++i)
#pragma unroll
      for (int j = 0; j < 4; ++j)
        acc[2 + i][j] = __builtin_amdgcn_mfma_f32_16x16x32_bf16(a[i], b0[j], acc[2 + i][j], 0, 0, 0);
    __builtin_amdgcn_s_setprio(0);

    // ---- phase 3: read A(i2,i3;k1); reuse B(k1); 8 MFMA ----
#pragma unroll
    for (int i = 0; i < 2; ++i)
      a[i] = *(const bf16x8*)(Ab + (wr * 64 + (2 + i) * 16 + lm) * 128 + (((4 + lg) ^ swz) << 4));
    __builtin_amdgcn_s_barrier();
    __builtin_amdgcn_s_setprio(1);
#pragma unroll
    for (int i = 0; i < 2; ++i)
#pragma unroll
      for (int j = 0; j < 4; ++j)
        acc[2 + i][j] = __builtin_amdgcn_mfma_f32_16x16x32_bf16(a[i], b1[j], acc[2 + i][j], 0, 0, 0);
    __builtin_amdgcn_s_setprio(0);

    sA = (sA == 2) ? 0 : sA + 1;
    sA2 = (sA2 == 2) ? 0 : sA2 + 1;
  }

  // ---- epilogue ----
#pragma unroll
  for (int i = 0; i < 4; ++i)
#pragma unroll
    for (int j = 0; j < 4; ++j)
#pragma unroll
      for (int r = 0; r < 4; ++r) {
        const size_t row = (size_t)(m0 + wr * 64 + i * 16 + lg * 4 + r);
        const size_t col = (size_t)(n0 + wc * 64 + j * 16 + lm);
        if (EMIT == 0) ((float*)Cout)[row * 2048 + col] = acc[i][j][r];
        else           ((__bf16*)Cout)[row * 2048 + col] = (__bf16)acc[i][j][r];
      }
}

// =====================================================================
// RoPE, in-place on bf16 tensor (b,s,h*hd); 4 elems (2 pairs) per thread.
// =====================================================================
__global__ __launch_bounds__(256) void rope_bf16(__bf16* __restrict__ t,
                                                 const float* __restrict__ cosp,
                                                 const float* __restrict__ sinp,
                                                 float scale) {
  const size_t i4 = (size_t)blockIdx.x * 256 + threadIdx.x;
  const size_t e = i4 * 4;
  const int srow = (int)((e >> 11) & 2047);
  const int p = (int)(e & 127) >> 1;
  bf16x4 vv = *(bf16x4*)(t + e);
  const float c0 = cosp[srow * 64 + p],     s0 = sinp[srow * 64 + p];
  const float c1 = cosp[srow * 64 + p + 1], s1 = sinp[srow * 64 + p + 1];
  const float re0 = (float)vv[0], im0 = (float)vv[1];
  const float re1 = (float)vv[2], im1 = (float)vv[3];
  bf16x4 o;
  o[0] = (__bf16)((re0 * c0 - im0 * s0) * scale);
  o[1] = (__bf16)((re0 * s0 + im0 * c0) * scale);
  o[2] = (__bf16)((re1 * c1 - im1 * s1) * scale);
  o[3] = (__bf16)((re1 * s1 + im1 * c1) * scale);
  *(bf16x4*)(t + e) = o;
}

// pack two floats to one dword of 2 bf16 (low = a)
static __device__ __forceinline__ unsigned pk2(float a, float b) {
  unsigned short x = __builtin_bit_cast(unsigned short, (__bf16)a);
  unsigned short y = __builtin_bit_cast(unsigned short, (__bf16)b);
  return ((unsigned)y << 16) | (unsigned)x;
}

// =====================================================================
// Flash attention v2 (unchanged from round 2, measured-good):
// 32x32x16 MFMA, swapped QK^T, in-register softmax/P, XOR-swizzled LDS.
// =====================================================================
__global__ __launch_bounds__(256) void attn_mfma2(const __bf16* __restrict__ q,
                                                  const __bf16* __restrict__ k,
                                                  const __bf16* __restrict__ v,
                                                  __bf16* __restrict__ oh,
                                                  __bf16* __restrict__ ol) {
  __shared__ __align__(16) char Ks[64 * 272];
  __shared__ __align__(16) char Vt[128 * 144];

  const int tid = threadIdx.x;
  const int l = tid & 63, w = tid >> 6;
  const int l31 = l & 31, hg = l >> 5;

  const int f = (int)blockIdx.x;
  const int X = f & 7, t = f >> 3;
  const int g = X * 4 + (t & 3);
  const int qt = 15 - (t >> 2);
  const int b = g >> 4, h = g & 15;
  const int q0 = qt * 128;
  const size_t bh = (size_t)b * SEQ * DMODEL + (size_t)h * HD;

  bf16x8 qf[8];
  {
    const __bf16* qr = q + bh + (size_t)(q0 + 32 * w + l31) * DMODEL;
#pragma unroll
    for (int ks = 0; ks < 8; ++ks) qf[ks] = *(const bf16x8*)(qr + ks * 16 + hg * 8);
  }

  f32x16 accO[4];
#pragma unroll
  for (int dt = 0; dt < 4; ++dt)
#pragma unroll
    for (int i = 0; i < 16; ++i) accO[dt][i] = 0.f;
  float m_own = -1e30f, l_own = 0.f;

  const int srT = tid >> 4;
  const int scT = tid & 15;
  const int nkt = 2 * qt + 2;
  const int qg_own = q0 + 32 * w + l31;
  const int qg_min = q0 + 32 * w;

  bf16x8 kst[4], vst[4];
#pragma unroll
  for (int rnd = 0; rnd < 4; ++rnd) {
    const int r = srT + 16 * rnd;
    const size_t ga = bh + (size_t)(r) * DMODEL + scT * 8;
    kst[rnd] = *(const bf16x8*)(k + ga);
    vst[rnd] = *(const bf16x8*)(v + ga);
  }

  for (int kt = 0; kt < nkt; ++kt) {
    const int k0 = kt * 64;
    __syncthreads();
#pragma unroll
    for (int rnd = 0; rnd < 4; ++rnd) {
      const int r = srT + 16 * rnd;
      *(bf16x8*)(Ks + r * 272 + ((scT * 16) ^ (((r >> 3) & 7) << 4))) = kst[rnd];
      const int swz = (scT & 7) << 4;
      const int cb = (2 * r) ^ swz;
#pragma unroll
      for (int e = 0; e < 8; ++e)
        *(__bf16*)(Vt + (scT * 8 + e) * 144 + cb) = vst[rnd][e];
    }
    __syncthreads();
    if (kt + 1 < nkt) {
#pragma unroll
      for (int rnd = 0; rnd < 4; ++rnd) {
        const int r = srT + 16 * rnd;
        const size_t ga = bh + (size_t)((kt + 1) * 64 + r) * DMODEL + scT * 8;
        kst[rnd] = *(const bf16x8*)(k + ga);
        vst[rnd] = *(const bf16x8*)(v + ga);
      }
    }
    if (k0 > qg_min + 31) continue;

    f32x16 sc[2];
#pragma unroll
    for (int mt = 0; mt < 2; ++mt)
#pragma unroll
      for (int i = 0; i < 16; ++i) sc[mt][i] = 0.f;
#pragma unroll
    for (int mt = 0; mt < 2; ++mt) {
      const int row = mt * 32 + l31;
      const char* kr = Ks + row * 272;
      const int sx = ((row >> 3) & 7) << 4;
#pragma unroll
      for (int ks = 0; ks < 8; ++ks) {
        bf16x8 kf = *(const bf16x8*)(kr + ((ks * 32 + hg * 16) ^ sx));
        sc[mt] = __builtin_amdgcn_mfma_f32_32x32x16_bf16(kf, qf[ks], sc[mt], 0, 0, 0);
      }
    }

    if (k0 + 63 > qg_min) {
#pragma unroll
      for (int mt = 0; mt < 2; ++mt)
#pragma unroll
        for (int ri = 0; ri < 16; ++ri) {
          const int kg = k0 + mt * 32 + (ri & 3) + 8 * (ri >> 2) + 4 * hg;
          if (kg > qg_own) sc[mt][ri] = -INFINITY;
        }
    }

    float tm = -INFINITY;
#pragma unroll
    for (int mt = 0; mt < 2; ++mt)
#pragma unroll
      for (int ri = 0; ri < 16; ++ri) tm = fmaxf(tm, sc[mt][ri]);
    tm = fmaxf(tm, __shfl_xor(tm, 32));

    if (__any(tm > m_own)) {
      const float mnew = fmaxf(m_own, tm);
      const float alpha = __expf(m_own - mnew);
      m_own = mnew;
      l_own *= alpha;
#pragma unroll
      for (int ri = 0; ri < 16; ++ri) {
        const float a = __shfl(alpha, (ri & 3) + 8 * (ri >> 2) + 4 * hg);
#pragma unroll
        for (int dt = 0; dt < 4; ++dt) accO[dt][ri] *= a;
      }
    }
    float rs = 0.f;
#pragma unroll
    for (int mt = 0; mt < 2; ++mt)
#pragma unroll
      for (int ri = 0; ri < 16; ++ri) {
        const float p = __expf(sc[mt][ri] - m_own);
        sc[mt][ri] = p;
        rs += p;
      }
    rs += __shfl_xor(rs, 32);
    l_own += rs;

#pragma unroll
    for (int kk = 0; kk < 4; ++kk) {
      const int mt = kk >> 1, J8 = (kk & 1) * 8;
      unsigned oL0 = pk2(sc[mt][J8 + 0], sc[mt][J8 + 1]);
      unsigned oL1 = pk2(sc[mt][J8 + 2], sc[mt][J8 + 3]);
      unsigned oH0 = pk2(sc[mt][J8 + 4], sc[mt][J8 + 5]);
      unsigned oH1 = pk2(sc[mt][J8 + 6], sc[mt][J8 + 7]);
      unsigned s0 = hg ? oL0 : oH0;
      unsigned s1 = hg ? oL1 : oH1;
      const unsigned r0 = (unsigned)__shfl_xor((int)s0, 32);
      const unsigned r1 = (unsigned)__shfl_xor((int)s1, 32);
      int4 fi;
      fi.x = (int)(hg ? r0 : oL0);
      fi.y = (int)(hg ? r1 : oL1);
      fi.z = (int)(hg ? oH0 : r0);
      fi.w = (int)(hg ? oH1 : r1);
      const bf16x8 pa = __builtin_bit_cast(bf16x8, fi);
      const int kb = (kk * 32 + hg * 16);
#pragma unroll
      for (int dt = 0; dt < 4; ++dt) {
        const int d = dt * 32 + l31;
        bf16x8 vf = *(const bf16x8*)(Vt + d * 144 + (kb ^ (((d >> 3) & 7) << 4)));
        accO[dt] = __builtin_amdgcn_mfma_f32_32x32x16_bf16(pa, vf, accO[dt], 0, 0, 0);
      }
    }
  }

  const float inv_own = 1.f / l_own;
#pragma unroll
  for (int ri = 0; ri < 16; ++ri) {
    const int row = (ri & 3) + 8 * (ri >> 2) + 4 * hg;
    const float il = __shfl(inv_own, row & 31);
    const size_t rbase = bh + (size_t)(q0 + 32 * w + row) * DMODEL;
#pragma unroll
    for (int dt = 0; dt < 4; ++dt) {
      const float val = accO[dt][ri] * il;
      const size_t idx = rbase + dt * 32 + l31;
      const __bf16 hv = (__bf16)val;
      oh[idx] = hv;
      ol[idx] = (__bf16)(val - (float)hv);
    }
  }
}

// =====================================================================
extern "C" void kernel_launch(void* const* d_in, const int* in_sizes, int n_in,
                              void* d_out, int out_size, void* d_ws, size_t ws_size,
                              hipStream_t stream) {
  const float* x  = (const float*)d_in[0];
  const float* wq = (const float*)d_in[1];
  const float* wk = (const float*)d_in[2];
  const float* wv = (const float*)d_in[3];
  const float* wo = (const float*)d_in[4];
  const float* fc = (const float*)d_in[5];
  const float* fs = (const float*)d_in[6];
  // d_in[7] (mask) not read: causal mask applied inline.

  const size_t NTOK = (size_t)BATCH * SEQ;        // 4096
  const size_t NE   = NTOK * DMODEL;              // 8,388,608

  char* wsb = (char*)d_ws;
  __bf16* xh = (__bf16*)wsb;
  __bf16* xl = xh + NE;
  __bf16* wh = (__bf16*)(wsb + 2 * NE * 2);
  __bf16* wl = wh + (size_t)DMODEL * DMODEL;
  __bf16* vb = (__bf16*)(wsb + 2 * NE * 2 + 2 * (size_t)DMODEL * DMODEL * 2);
  __bf16* oh = xh;                                // reuse x-split after QKV gemms
  __bf16* ol = xl;
  __bf16* qb = (__bf16*)d_out;                    // scratch in d_out
  __bf16* kb = qb + NE;

  const int sx = (int)(NE / 4 / 256);
  const int sw = DMODEL * DMODEL / 4 / 256;
  const int SMEM = 131072;                        // 128 KiB dynamic LDS

  // opt-in to >64KB dynamic LDS (no-op / ignored error if not needed)
  (void)hipFuncSetAttribute((const void*)gemm8<1>,
                            hipFuncAttributeMaxDynamicSharedMemorySize, SMEM);
  (void)hipFuncSetAttribute((const void*)gemm8<0>,
                            hipFuncAttributeMaxDynamicSharedMemorySize, SMEM);

  split_fp32<<<sx, 256, 0, stream>>>(x, xh, xl);

  split_fp32<<<sw, 256, 0, stream>>>(wq, wh, wl);
  gemm8<1><<<256, 512, SMEM, stream>>>(xh, xl, wh, wl, qb);
  split_fp32<<<sw, 256, 0, stream>>>(wk, wh, wl);
  gemm8<1><<<256, 512, SMEM, stream>>>(xh, xl, wh, wl, kb);
  split_fp32<<<sw, 256, 0, stream>>>(wv, wh, wl);
  gemm8<1><<<256, 512, SMEM, stream>>>(xh, xl, wh, wl, vb);

  rope_bf16<<<sx, 256, 0, stream>>>(qb, fc, fs, 0.08838834764831845f);
  rope_bf16<<<sx, 256, 0, stream>>>(kb, fc, fs, 1.0f);

  attn_mfma2<<<dim3(512), 256, 0, stream>>>(qb, kb, vb, oh, ol);

  split_fp32<<<sw, 256, 0, stream>>>(wo, wh, wl);
  gemm8<0><<<256, 512, SMEM, stream>>>(oh, ol, wh, wl, (float*)d_out);
}

// Round 7
// 651.054 us; speedup vs baseline: 1.0344x; 1.0344x over previous
//
#include <hip/hip_runtime.h>
#include <math.h>

#define BATCH 2
#define SEQ 2048
#define DMODEL 2048
#define NH 16
#define HD 128

typedef __bf16 bf16x8 __attribute__((ext_vector_type(8)));
typedef __bf16 bf16x4 __attribute__((ext_vector_type(4)));
typedef float f32x4 __attribute__((ext_vector_type(4)));
typedef float f32x16 __attribute__((ext_vector_type(16)));

// async global->LDS, 16B per lane; dst must be wave-uniform, HW adds lane*16
#define GLL16(dst, src)                                                          \
  __builtin_amdgcn_global_load_lds(                                              \
      (const __attribute__((address_space(1))) void*)(src),                      \
      (__attribute__((address_space(3))) void*)(dst), 16, 0, 0)

// =====================================================================
// split fp32 -> bf16 hi + bf16 lo  (hi = rne(v), lo = rne(v - hi))
// =====================================================================
__global__ __launch_bounds__(256) void split_fp32(const float* __restrict__ src,
                                                  __bf16* __restrict__ hi,
                                                  __bf16* __restrict__ lo) {
  const size_t i = (size_t)blockIdx.x * 256 + threadIdx.x;
  const float4 v = ((const float4*)src)[i];
  bf16x4 h, L;
  h[0] = (__bf16)v.x; h[1] = (__bf16)v.y; h[2] = (__bf16)v.z; h[3] = (__bf16)v.w;
  L[0] = (__bf16)(v.x - (float)h[0]);
  L[1] = (__bf16)(v.y - (float)h[1]);
  L[2] = (__bf16)(v.z - (float)h[2]);
  L[3] = (__bf16)(v.w - (float)h[3]);
  ((bf16x4*)hi)[i] = h;
  ((bf16x4*)lo)[i] = L;
}

// =====================================================================
// Deep-pipelined split GEMM (NT): C[4096,2048] = (Ah+Al).((Bh+Bl))^T
// via K'=3K: segments (Ah,Bh),(Al,Bh),(Ah,Bl) over K'=6144.
// BM=256 BN=128 BK=64, 8 waves (4Mx2N), per-wave 64x64.
// LDS 128 KiB: A triple-buffered (3x32K), B double-buffered (2x16K).
// Per tile: [vmcnt(4); barrier] then TWO phases of
// {8 ds_read_b128; stage-issue; barrier; setprio; 16 MFMA; setprio}.
// (Round-6 post-mortem: 4 phases of 8 MFMA gave 41% duty; 16-MFMA
//  clusters predicted ~60%.) Staging/vmcnt identical to validated r6.
// =====================================================================
template <int EMIT>
__global__ __launch_bounds__(512, 2) void gemm8(const __bf16* __restrict__ Ah,
                                                const __bf16* __restrict__ Al,
                                                const __bf16* __restrict__ Bh,
                                                const __bf16* __restrict__ Bl,
                                                void* __restrict__ Cout) {
  extern __shared__ char sm[];          // 128 KiB dynamic
  constexpr int NT = 96;                // 6144 / 64
  const int tid = threadIdx.x;
  const int l = tid & 63, w = tid >> 6;
  const int lg = l >> 4, lm = l & 15;
  const int wr = w >> 1, wc = w & 1;    // wave grid 4M x 2N

  // XCD-aware 2D block decode: XCD X gets a 4mb x 8nb rectangle
  const int bid = (int)blockIdx.x;
  const int X = bid & 7, sub = bid >> 3;
  const int mb = (X & 3) * 4 + (sub >> 3);
  const int nb = (X >> 2) * 8 + (sub & 7);
  const int m0 = mb * 256, n0 = nb * 128;

  const __bf16* segA[3] = {Ah, Al, Ah};
  const __bf16* segB[3] = {Bh, Bh, Bl};

  // staging lane constants: 8-row groups, swizzled 16B chunk
  const int srow = l >> 3;                   // 0..7
  const int co = ((l & 7) ^ srow) * 8;       // element offset of 16B chunk

  // LDS map: A slots at 0/32K/64K (each 256 rows x 128B); B at 96K/112K
  char* const Abuf = sm;
  char* const Bbuf = sm + 98304;

  auto stageB = [&](int tb) {                // 2 gll per thread
    char* bd = Bbuf + (tb & 1) * 16384;
    const __bf16* sb = segB[tb >> 5];
    const int kw = (tb & 31) * 64;
#pragma unroll
    for (int j = 0; j < 2; ++j)
      GLL16(bd + (w * 2 + j) * 1024,
            sb + (size_t)(n0 + (w * 2 + j) * 8 + srow) * 2048 + kw + co);
  };
  auto stageAu = [&](int ta, int slot, int u) {   // 2 gll per thread
    char* ad = Abuf + slot * 32768 + u * 16384;
    const __bf16* sa = segA[ta >> 5];
    const int kw = (ta & 31) * 64;
#pragma unroll
    for (int j = 0; j < 2; ++j)
      GLL16(ad + (w * 2 + j) * 1024,
            sa + (size_t)(m0 + u * 128 + (w * 2 + j) * 8 + srow) * 2048 + kw + co);
  };

  // ---- prologue: A(0)->slot0; B(0); A(1)->slot1 ----
  stageAu(0, 0, 0); stageAu(0, 0, 1);
  stageB(0);
  stageAu(1, 1, 0); stageAu(1, 1, 1);

  f32x4 acc[4][4];
#pragma unroll
  for (int i = 0; i < 4; ++i)
#pragma unroll
    for (int j = 0; j < 4; ++j) { f32x4 z = {0.f, 0.f, 0.f, 0.f}; acc[i][j] = z; }

  int sA = 0, sA2 = 2;   // A read slot (t%3), A stage slot ((t+2)%3)
  const int swz = lm & 7;

  for (int t = 0; t < NT; ++t) {
    // ---- tile top: counted wait + barrier (tile-t data visible to all)
    if (t + 1 < NT) { asm volatile("s_waitcnt vmcnt(4)" ::: "memory"); }
    else            { asm volatile("s_waitcnt vmcnt(0)" ::: "memory"); }
    __builtin_amdgcn_sched_barrier(0);
    __builtin_amdgcn_s_barrier();

    const char* Ab = Abuf + sA * 32768;
    const char* Bb = Bbuf + (t & 1) * 16384;
    bf16x8 a[4], b[4];

    // ======== phase 0: k-half 0 — 8 reads, stage, 16 MFMA ========
#pragma unroll
    for (int j = 0; j < 4; ++j)
      b[j] = *(const bf16x8*)(Bb + (wc * 64 + j * 16 + lm) * 128 + ((lg ^ swz) << 4));
#pragma unroll
    for (int i = 0; i < 4; ++i)
      a[i] = *(const bf16x8*)(Ab + (wr * 64 + i * 16 + lm) * 128 + ((lg ^ swz) << 4));
    if (t + 1 < NT) stageB(t + 1);
    if (t + 2 < NT) stageAu(t + 2, sA2, 0);
    __builtin_amdgcn_s_barrier();
    __builtin_amdgcn_s_setprio(1);
#pragma unroll
    for (int i = 0; i < 4; ++i)
#pragma unroll
      for (int j = 0; j < 4; ++j)
        acc[i][j] = __builtin_amdgcn_mfma_f32_16x16x32_bf16(a[i], b[j], acc[i][j], 0, 0, 0);
    __builtin_amdgcn_s_setprio(0);

    // ======== phase 1: k-half 1 — 8 reads, stage, 16 MFMA ========
#pragma unroll
    for (int j = 0; j < 4; ++j)
      b[j] = *(const bf16x8*)(Bb + (wc * 64 + j * 16 + lm) * 128 + (((4 + lg) ^ swz) << 4));
#pragma unroll
    for (int i = 0; i < 4; ++i)
      a[i] = *(const bf16x8*)(Ab + (wr * 64 + i * 16 + lm) * 128 + (((4 + lg) ^ swz) << 4));
    if (t + 2 < NT) stageAu(t + 2, sA2, 1);
    __builtin_amdgcn_s_barrier();
    __builtin_amdgcn_s_setprio(1);
#pragma unroll
    for (int i = 0; i < 4; ++i)
#pragma unroll
      for (int j = 0; j < 4; ++j)
        acc[i][j] = __builtin_amdgcn_mfma_f32_16x16x32_bf16(a[i], b[j], acc[i][j], 0, 0, 0);
    __builtin_amdgcn_s_setprio(0);

    sA = (sA == 2) ? 0 : sA + 1;
    sA2 = (sA2 == 2) ? 0 : sA2 + 1;
  }

  // ---- epilogue ----
#pragma unroll
  for (int i = 0; i < 4; ++i)
#pragma unroll
    for (int j = 0; j < 4; ++j)
#pragma unroll
      for (int r = 0; r < 4; ++r) {
        const size_t row = (size_t)(m0 + wr * 64 + i * 16 + lg * 4 + r);
        const size_t col = (size_t)(n0 + wc * 64 + j * 16 + lm);
        if (EMIT == 0) ((float*)Cout)[row * 2048 + col] = acc[i][j][r];
        else           ((__bf16*)Cout)[row * 2048 + col] = (__bf16)acc[i][j][r];
      }
}

// =====================================================================
// RoPE, in-place, q and k in one launch (blockIdx.y: 0=q w/ scale, 1=k).
// =====================================================================
__global__ __launch_bounds__(256) void rope_bf16(__bf16* __restrict__ q,
                                                 __bf16* __restrict__ k,
                                                 const float* __restrict__ cosp,
                                                 const float* __restrict__ sinp) {
  __bf16* t = blockIdx.y ? k : q;
  const float scale = blockIdx.y ? 1.0f : 0.08838834764831845f;  // 1/sqrt(128)
  const size_t i4 = (size_t)blockIdx.x * 256 + threadIdx.x;
  const size_t e = i4 * 4;
  const int srow = (int)((e >> 11) & 2047);
  const int p = (int)(e & 127) >> 1;
  bf16x4 vv = *(bf16x4*)(t + e);
  const float c0 = cosp[srow * 64 + p],     s0 = sinp[srow * 64 + p];
  const float c1 = cosp[srow * 64 + p + 1], s1 = sinp[srow * 64 + p + 1];
  const float re0 = (float)vv[0], im0 = (float)vv[1];
  const float re1 = (float)vv[2], im1 = (float)vv[3];
  bf16x4 o;
  o[0] = (__bf16)((re0 * c0 - im0 * s0) * scale);
  o[1] = (__bf16)((re0 * s0 + im0 * c0) * scale);
  o[2] = (__bf16)((re1 * c1 - im1 * s1) * scale);
  o[3] = (__bf16)((re1 * s1 + im1 * c1) * scale);
  *(bf16x4*)(t + e) = o;
}

// pack two floats to one dword of 2 bf16 (low = a)
static __device__ __forceinline__ unsigned pk2(float a, float b) {
  unsigned short x = __builtin_bit_cast(unsigned short, (__bf16)a);
  unsigned short y = __builtin_bit_cast(unsigned short, (__bf16)b);
  return ((unsigned)y << 16) | (unsigned)x;
}

// =====================================================================
// Flash attention v2 (unchanged, measured-good):
// 32x32x16 MFMA, swapped QK^T, in-register softmax/P, XOR-swizzled LDS.
// =====================================================================
__global__ __launch_bounds__(256) void attn_mfma2(const __bf16* __restrict__ q,
                                                  const __bf16* __restrict__ k,
                                                  const __bf16* __restrict__ v,
                                                  __bf16* __restrict__ oh,
                                                  __bf16* __restrict__ ol) {
  __shared__ __align__(16) char Ks[64 * 272];
  __shared__ __align__(16) char Vt[128 * 144];

  const int tid = threadIdx.x;
  const int l = tid & 63, w = tid >> 6;
  const int l31 = l & 31, hg = l >> 5;

  const int f = (int)blockIdx.x;
  const int X = f & 7, t = f >> 3;
  const int g = X * 4 + (t & 3);
  const int qt = 15 - (t >> 2);
  const int b = g >> 4, h = g & 15;
  const int q0 = qt * 128;
  const size_t bh = (size_t)b * SEQ * DMODEL + (size_t)h * HD;

  bf16x8 qf[8];
  {
    const __bf16* qr = q + bh + (size_t)(q0 + 32 * w + l31) * DMODEL;
#pragma unroll
    for (int ks = 0; ks < 8; ++ks) qf[ks] = *(const bf16x8*)(qr + ks * 16 + hg * 8);
  }

  f32x16 accO[4];
#pragma unroll
  for (int dt = 0; dt < 4; ++dt)
#pragma unroll
    for (int i = 0; i < 16; ++i) accO[dt][i] = 0.f;
  float m_own = -1e30f, l_own = 0.f;

  const int srT = tid >> 4;
  const int scT = tid & 15;
  const int nkt = 2 * qt + 2;
  const int qg_own = q0 + 32 * w + l31;
  const int qg_min = q0 + 32 * w;

  bf16x8 kst[4], vst[4];
#pragma unroll
  for (int rnd = 0; rnd < 4; ++rnd) {
    const int r = srT + 16 * rnd;
    const size_t ga = bh + (size_t)(r) * DMODEL + scT * 8;
    kst[rnd] = *(const bf16x8*)(k + ga);
    vst[rnd] = *(const bf16x8*)(v + ga);
  }

  for (int kt = 0; kt < nkt; ++kt) {
    const int k0 = kt * 64;
    __syncthreads();
#pragma unroll
    for (int rnd = 0; rnd < 4; ++rnd) {
      const int r = srT + 16 * rnd;
      *(bf16x8*)(Ks + r * 272 + ((scT * 16) ^ (((r >> 3) & 7) << 4))) = kst[rnd];
      const int swz = (scT & 7) << 4;
      const int cb = (2 * r) ^ swz;
#pragma unroll
      for (int e = 0; e < 8; ++e)
        *(__bf16*)(Vt + (scT * 8 + e) * 144 + cb) = vst[rnd][e];
    }
    __syncthreads();
    if (kt + 1 < nkt) {
#pragma unroll
      for (int rnd = 0; rnd < 4; ++rnd) {
        const int r = srT + 16 * rnd;
        const size_t ga = bh + (size_t)((kt + 1) * 64 + r) * DMODEL + scT * 8;
        kst[rnd] = *(const bf16x8*)(k + ga);
        vst[rnd] = *(const bf16x8*)(v + ga);
      }
    }
    if (k0 > qg_min + 31) continue;

    f32x16 sc[2];
#pragma unroll
    for (int mt = 0; mt < 2; ++mt)
#pragma unroll
      for (int i = 0; i < 16; ++i) sc[mt][i] = 0.f;
#pragma unroll
    for (int mt = 0; mt < 2; ++mt) {
      const int row = mt * 32 + l31;
      const char* kr = Ks + row * 272;
      const int sx = ((row >> 3) & 7) << 4;
#pragma unroll
      for (int ks = 0; ks < 8; ++ks) {
        bf16x8 kf = *(const bf16x8*)(kr + ((ks * 32 + hg * 16) ^ sx));
        sc[mt] = __builtin_amdgcn_mfma_f32_32x32x16_bf16(kf, qf[ks], sc[mt], 0, 0, 0);
      }
    }

    if (k0 + 63 > qg_min) {
#pragma unroll
      for (int mt = 0; mt < 2; ++mt)
#pragma unroll
        for (int ri = 0; ri < 16; ++ri) {
          const int kg = k0 + mt * 32 + (ri & 3) + 8 * (ri >> 2) + 4 * hg;
          if (kg > qg_own) sc[mt][ri] = -INFINITY;
        }
    }

    float tm = -INFINITY;
#pragma unroll
    for (int mt = 0; mt < 2; ++mt)
#pragma unroll
      for (int ri = 0; ri < 16; ++ri) tm = fmaxf(tm, sc[mt][ri]);
    tm = fmaxf(tm, __shfl_xor(tm, 32));

    if (__any(tm > m_own)) {
      const float mnew = fmaxf(m_own, tm);
      const float alpha = __expf(m_own - mnew);
      m_own = mnew;
      l_own *= alpha;
#pragma unroll
      for (int ri = 0; ri < 16; ++ri) {
        const float a = __shfl(alpha, (ri & 3) + 8 * (ri >> 2) + 4 * hg);
#pragma unroll
        for (int dt = 0; dt < 4; ++dt) accO[dt][ri] *= a;
      }
    }
    float rs = 0.f;
#pragma unroll
    for (int mt = 0; mt < 2; ++mt)
#pragma unroll
      for (int ri = 0; ri < 16; ++ri) {
        const float p = __expf(sc[mt][ri] - m_own);
        sc[mt][ri] = p;
        rs += p;
      }
    rs += __shfl_xor(rs, 32);
    l_own += rs;

#pragma unroll
    for (int kk = 0; kk < 4; ++kk) {
      const int mt = kk >> 1, J8 = (kk & 1) * 8;
      unsigned oL0 = pk2(sc[mt][J8 + 0], sc[mt][J8 + 1]);
      unsigned oL1 = pk2(sc[mt][J8 + 2], sc[mt][J8 + 3]);
      unsigned oH0 = pk2(sc[mt][J8 + 4], sc[mt][J8 + 5]);
      unsigned oH1 = pk2(sc[mt][J8 + 6], sc[mt][J8 + 7]);
      unsigned s0 = hg ? oL0 : oH0;
      unsigned s1 = hg ? oL1 : oH1;
      const unsigned r0 = (unsigned)__shfl_xor((int)s0, 32);
      const unsigned r1 = (unsigned)__shfl_xor((int)s1, 32);
      int4 fi;
      fi.x = (int)(hg ? r0 : oL0);
      fi.y = (int)(hg ? r1 : oL1);
      fi.z = (int)(hg ? oH0 : r0);
      fi.w = (int)(hg ? oH1 : r1);
      const bf16x8 pa = __builtin_bit_cast(bf16x8, fi);
      const int kb = (kk * 32 + hg * 16);
#pragma unroll
      for (int dt = 0; dt < 4; ++dt) {
        const int d = dt * 32 + l31;
        bf16x8 vf = *(const bf16x8*)(Vt + d * 144 + (kb ^ (((d >> 3) & 7) << 4)));
        accO[dt] = __builtin_amdgcn_mfma_f32_32x32x16_bf16(pa, vf, accO[dt], 0, 0, 0);
      }
    }
  }

  const float inv_own = 1.f / l_own;
#pragma unroll
  for (int ri = 0; ri < 16; ++ri) {
    const int row = (ri & 3) + 8 * (ri >> 2) + 4 * hg;
    const float il = __shfl(inv_own, row & 31);
    const size_t rbase = bh + (size_t)(q0 + 32 * w + row) * DMODEL;
#pragma unroll
    for (int dt = 0; dt < 4; ++dt) {
      const float val = accO[dt][ri] * il;
      const size_t idx = rbase + dt * 32 + l31;
      const __bf16 hv = (__bf16)val;
      oh[idx] = hv;
      ol[idx] = (__bf16)(val - (float)hv);
    }
  }
}

// =====================================================================
extern "C" void kernel_launch(void* const* d_in, const int* in_sizes, int n_in,
                              void* d_out, int out_size, void* d_ws, size_t ws_size,
                              hipStream_t stream) {
  const float* x  = (const float*)d_in[0];
  const float* wq = (const float*)d_in[1];
  const float* wk = (const float*)d_in[2];
  const float* wv = (const float*)d_in[3];
  const float* wo = (const float*)d_in[4];
  const float* fc = (const float*)d_in[5];
  const float* fs = (const float*)d_in[6];
  // d_in[7] (mask) not read: causal mask applied inline.

  const size_t NTOK = (size_t)BATCH * SEQ;        // 4096
  const size_t NE   = NTOK * DMODEL;              // 8,388,608

  char* wsb = (char*)d_ws;
  __bf16* xh = (__bf16*)wsb;
  __bf16* xl = xh + NE;
  __bf16* wh = (__bf16*)(wsb + 2 * NE * 2);
  __bf16* wl = wh + (size_t)DMODEL * DMODEL;
  __bf16* vb = (__bf16*)(wsb + 2 * NE * 2 + 2 * (size_t)DMODEL * DMODEL * 2);
  __bf16* oh = xh;                                // reuse x-split after QKV gemms
  __bf16* ol = xl;
  __bf16* qb = (__bf16*)d_out;                    // scratch in d_out
  __bf16* kb = qb + NE;

  const int sx = (int)(NE / 4 / 256);
  const int sw = DMODEL * DMODEL / 4 / 256;
  const int SMEM = 131072;                        // 128 KiB dynamic LDS

  (void)hipFuncSetAttribute((const void*)gemm8<1>,
                            hipFuncAttributeMaxDynamicSharedMemorySize, SMEM);
  (void)hipFuncSetAttribute((const void*)gemm8<0>,
                            hipFuncAttributeMaxDynamicSharedMemorySize, SMEM);

  split_fp32<<<sx, 256, 0, stream>>>(x, xh, xl);

  split_fp32<<<sw, 256, 0, stream>>>(wq, wh, wl);
  gemm8<1><<<256, 512, SMEM, stream>>>(xh, xl, wh, wl, qb);
  split_fp32<<<sw, 256, 0, stream>>>(wk, wh, wl);
  gemm8<1><<<256, 512, SMEM, stream>>>(xh, xl, wh, wl, kb);
  split_fp32<<<sw, 256, 0, stream>>>(wv, wh, wl);
  gemm8<1><<<256, 512, SMEM, stream>>>(xh, xl, wh, wl, vb);

  rope_bf16<<<dim3(sx, 2), 256, 0, stream>>>(qb, kb, fc, fs);

  attn_mfma2<<<dim3(512), 256, 0, stream>>>(qb, kb, vb, oh, ol);

  split_fp32<<<sw, 256, 0, stream>>>(wo, wh, wl);
  gemm8<0><<<256, 512, SMEM, stream>>>(oh, ol, wh, wl, (float*)d_out);
}